// Round 8
// baseline (314.214 us; speedup 1.0000x reference)
//
#include <hip/hip_runtime.h>
#include <hip/hip_bf16.h>

// N=50000 nodes, E=800000 edges, D=96 (in = hidden = out)
#define NNODES 50000
#define NEDGES 800000
#define DIM    96
#define SCAN_B 256
#define NB     ((NNODES + SCAN_B - 1) / SCAN_B)   // 196 scan blocks
#define TM     64                                  // rows per GEMM block
#define XPAD   104                                 // LDS row stride (bf16), 16B-aligned

typedef __attribute__((ext_vector_type(8))) short   short8;   // 8 bf16 = 4 VGPRs
typedef __attribute__((ext_vector_type(4))) float   float4v;  // MFMA acc
typedef __attribute__((ext_vector_type(2))) int     int2v;    // for nontemporal loads
typedef __attribute__((ext_vector_type(4))) int     int4v;

// flags[0] = 1 if float tensors are bf16, 0 if f32
// flags[1] = 1 if edge_index is int64, 0 if int32
__device__ __forceinline__ float loadF(const void* p, long i, int isbf) {
    return isbf ? __bfloat162float(((const __hip_bfloat16*)p)[i])
                : ((const float*)p)[i];
}
__device__ __forceinline__ int clampN(int v) {
    return v < 0 ? 0 : (v >= NNODES ? NNODES - 1 : v);
}

// single wave: sniff x's float dtype and edge_index's int width
__global__ void k_sniff(const unsigned* __restrict__ xw,
                        const unsigned* __restrict__ ew,
                        int* __restrict__ flags) {
    int lane = threadIdx.x;
    int bad = 0, nz = 0;
    for (int r = 0; r < 4; ++r) {
        unsigned w  = xw[lane + 64 * r];
        unsigned lo = w & 0xffffu;
        unsigned ex = (lo >> 7) & 0xffu;
        if (!(lo == 0u || (ex >= 90u && ex <= 145u))) bad++;
        unsigned o = ew[2 * (lane + 64 * r) + 1];
        if (o != 0u) nz++;
    }
    for (int off = 32; off; off >>= 1) {
        bad += __shfl_down(bad, off);
        nz  += __shfl_down(nz,  off);
    }
    if (lane == 0) {
        flags[0] = (bad <= 32) ? 1 : 0;
        flags[1] = (nz  <  4) ? 1 : 0;
    }
}

// cnt[dst]++ for 2 edges/thread; nontemporal edge reads (don't evict L2)
__global__ void k_count(const int* __restrict__ w, int* __restrict__ cnt,
                        const int* __restrict__ flags) {
    int t = blockIdx.x * blockDim.x + threadIdx.x;
    if (2 * t >= NEDGES) return;
    int d0, d1;
    if (flags[1]) {
        int4v v = __builtin_nontemporal_load((const int4v*)(w + 2 * NEDGES + 4 * t));
        d0 = v.x; d1 = v.z;
    } else {
        int2v v = __builtin_nontemporal_load((const int2v*)(w + NEDGES + 2 * t));
        d0 = v.x; d1 = v.y;
    }
    atomicAdd(&cnt[clampN(d0)], 1);
    atomicAdd(&cnt[clampN(d1)], 1);
}

// exclusive scan of cnt -> rowptr; also dinv = rsqrt(cnt+1) (fused)
__global__ void k_scan1(const int* __restrict__ cnt, int* __restrict__ rowptr,
                        int* __restrict__ bsum, float* __restrict__ dinv) {
    __shared__ int s[SCAN_B];
    int i = blockIdx.x * SCAN_B + threadIdx.x;
    int v = (i < NNODES) ? cnt[i] : 0;
    if (i < NNODES) dinv[i] = rsqrtf((float)v + 1.0f);   // +1 self loop
    s[threadIdx.x] = v;
    __syncthreads();
    for (int off = 1; off < SCAN_B; off <<= 1) {
        int t = (threadIdx.x >= off) ? s[threadIdx.x - off] : 0;
        __syncthreads();
        s[threadIdx.x] += t;
        __syncthreads();
    }
    if (i < NNODES) rowptr[i] = s[threadIdx.x] - v;
    if (threadIdx.x == SCAN_B - 1) bsum[blockIdx.x] = s[SCAN_B - 1];
}

__global__ void k_scan2(int* __restrict__ bsum) {       // 1 block of 256
    __shared__ int s[SCAN_B];
    int v = (threadIdx.x < NB) ? bsum[threadIdx.x] : 0;
    s[threadIdx.x] = v;
    __syncthreads();
    for (int off = 1; off < SCAN_B; off <<= 1) {
        int t = (threadIdx.x >= off) ? s[threadIdx.x - off] : 0;
        __syncthreads();
        s[threadIdx.x] += t;
        __syncthreads();
    }
    if (threadIdx.x < NB) bsum[threadIdx.x] = s[threadIdx.x] - v;
}

__global__ void k_scan3(int* __restrict__ rowptr, const int* __restrict__ bsum) {
    int i = blockIdx.x * SCAN_B + threadIdx.x;
    if (i < NNODES) rowptr[i] += bsum[blockIdx.x];
    if (i == 0) rowptr[NNODES] = NEDGES;
}

// CSR fill, 2 edges/thread; col[] is uint16 (N<65536) written nontemporally
// to avoid cross-XCD L2 line ping-pong on random scatter stores.
__global__ void k_fill(const int* __restrict__ w, const int* __restrict__ rowptr,
                       int* __restrict__ cur, unsigned short* __restrict__ col,
                       const int* __restrict__ flags) {
    int t = blockIdx.x * blockDim.x + threadIdx.x;
    if (2 * t >= NEDGES) return;
    int s0, s1, d0, d1;
    if (flags[1]) {
        int4v sv = __builtin_nontemporal_load((const int4v*)(w + 4 * t));
        int4v dv = __builtin_nontemporal_load((const int4v*)(w + 2 * NEDGES + 4 * t));
        s0 = sv.x; s1 = sv.z; d0 = dv.x; d1 = dv.z;
    } else {
        int2v sv = __builtin_nontemporal_load((const int2v*)(w + 2 * t));
        int2v dv = __builtin_nontemporal_load((const int2v*)(w + NEDGES + 2 * t));
        s0 = sv.x; s1 = sv.y; d0 = dv.x; d1 = dv.y;
    }
    s0 = clampN(s0); d0 = clampN(d0);
    s1 = clampN(s1); d1 = clampN(d1);
    int p0 = rowptr[d0] + atomicAdd(&cur[d0], 1);
    __builtin_nontemporal_store((unsigned short)s0, col + p0);
    int p1 = rowptr[d1] + atomicAdd(&cur[d1], 1);
    __builtin_nontemporal_store((unsigned short)s1, col + p1);
}

// MFMA GEMM: g[row,:] = bf16( dinv[row] * (X[row,:] @ W) )
// block = 256 (4 waves), 64 rows/block; X strip + W^T staged in LDS as bf16.
__global__ __launch_bounds__(256) void k_gemm_mfma(
        const void* __restrict__ X, int x_force_bf16,
        const void* __restrict__ W,
        const float* __restrict__ dinv,
        __hip_bfloat16* __restrict__ g,
        const int* __restrict__ flags) {
    __shared__ __hip_bfloat16 Xs[TM * XPAD];
    __shared__ __hip_bfloat16 Wt[DIM * XPAD];

    const int t    = threadIdx.x;
    const int fbf  = flags[0];
    const int xbf  = x_force_bf16 ? 1 : fbf;
    const int row0 = blockIdx.x * TM;

    for (int idx = t; idx < DIM * DIM; idx += 256) {
        int k = idx / DIM, n = idx - k * DIM;
        Wt[n * XPAD + k] = __float2bfloat16(loadF(W, idx, fbf));
    }
    for (int idx = t; idx < TM * DIM; idx += 256) {
        int r = idx / DIM, c = idx - r * DIM;
        int gr = row0 + r;
        float v = (gr < NNODES) ? loadF(X, (long)gr * DIM + c, xbf) : 0.f;
        Xs[r * XPAD + c] = __float2bfloat16(v);
    }
    __syncthreads();

    const int wave = t >> 6;
    const int lane = t & 63;
    const int m    = lane & 15;
    const int quad = lane >> 4;

    const short* xsp = (const short*)Xs;
    short8 a[3];
#pragma unroll
    for (int kt = 0; kt < 3; ++kt)
        a[kt] = *(const short8*)(xsp + (wave * 16 + m) * XPAD + kt * 32 + quad * 8);

    float dv[4];
#pragma unroll
    for (int r2 = 0; r2 < 4; ++r2) {
        int gr = row0 + wave * 16 + quad * 4 + r2;
        dv[r2] = (gr < NNODES) ? dinv[gr] : 0.f;
    }

    const short* wtp = (const short*)Wt;
#pragma unroll
    for (int nt = 0; nt < 6; ++nt) {
        float4v acc = {0.f, 0.f, 0.f, 0.f};
#pragma unroll
        for (int kt = 0; kt < 3; ++kt) {
            short8 b = *(const short8*)(wtp + (nt * 16 + m) * XPAD + kt * 32 + quad * 8);
            acc = __builtin_amdgcn_mfma_f32_16x16x32_bf16(a[kt], b, acc, 0, 0, 0);
        }
#pragma unroll
        for (int r2 = 0; r2 < 4; ++r2) {
            int gr = row0 + wave * 16 + quad * 4 + r2;
            if (gr < NNODES)
                g[(size_t)gr * DIM + nt * 16 + m] = __float2bfloat16(acc[r2] * dv[r2]);
        }
    }
}

// aggregate + epilogue: ONE WAVE per destination row, lanes 0..47 hold
// bfloat162 column pairs. col[] reads are wave-uniform.
__global__ __launch_bounds__(256) void k_aggr(
        const __hip_bfloat16* __restrict__ g,
        const int* __restrict__ rowptr,
        const unsigned short* __restrict__ col,
        const float* __restrict__ dinv,
        const void* __restrict__ b,
        const void* __restrict__ a1,
        void* __restrict__ out,
        const int* __restrict__ flags, int prelu) {
    const int wave = threadIdx.x >> 6;
    const int lane = threadIdx.x & 63;
    const int row  = blockIdx.x * 4 + wave;
    if (row >= NNODES) return;                       // wave-uniform
    const int fbf = flags[0];
    const __hip_bfloat162* gv = (const __hip_bfloat162*)g;
    const int c = lane;                              // 0..47 active

    float2 acc = {0.f, 0.f};
    if (c < 48) acc = __bfloat1622float2(gv[(size_t)row * 48 + c]);  // self loop

    const int p0 = rowptr[row], p1 = rowptr[row + 1];
    int i = p0;
    for (; i + 8 <= p1; i += 8) {
        int s0 = col[i+0], s1 = col[i+1], s2 = col[i+2], s3 = col[i+3];
        int s4 = col[i+4], s5 = col[i+5], s6 = col[i+6], s7 = col[i+7];
        if (c < 48) {
            float2 v0 = __bfloat1622float2(gv[(size_t)s0 * 48 + c]);
            float2 v1 = __bfloat1622float2(gv[(size_t)s1 * 48 + c]);
            float2 v2 = __bfloat1622float2(gv[(size_t)s2 * 48 + c]);
            float2 v3 = __bfloat1622float2(gv[(size_t)s3 * 48 + c]);
            float2 v4 = __bfloat1622float2(gv[(size_t)s4 * 48 + c]);
            float2 v5 = __bfloat1622float2(gv[(size_t)s5 * 48 + c]);
            float2 v6 = __bfloat1622float2(gv[(size_t)s6 * 48 + c]);
            float2 v7 = __bfloat1622float2(gv[(size_t)s7 * 48 + c]);
            acc.x += ((v0.x + v1.x) + (v2.x + v3.x)) + ((v4.x + v5.x) + (v6.x + v7.x));
            acc.y += ((v0.y + v1.y) + (v2.y + v3.y)) + ((v4.y + v5.y) + (v6.y + v7.y));
        }
    }
    for (; i < p1; ++i) {
        int s = col[i];
        if (c < 48) {
            float2 v = __bfloat1622float2(gv[(size_t)s * 48 + c]);
            acc.x += v.x; acc.y += v.y;
        }
    }

    if (c < 48) {
        float dv = dinv[row];
        float vx = dv * acc.x + loadF(b, 2 * c,     fbf);
        float vy = dv * acc.y + loadF(b, 2 * c + 1, fbf);
        if (prelu) {
            float alpha = loadF(a1, 0, fbf);
            vx = vx > 0.f ? vx : alpha * vx;
            vy = vy > 0.f ? vy : alpha * vy;
            ((__hip_bfloat162*)out)[(size_t)row * 48 + c] =
                __halves2bfloat162(__float2bfloat16(vx), __float2bfloat16(vy));
        } else if (fbf) {
            ((__hip_bfloat162*)out)[(size_t)row * 48 + c] =
                __halves2bfloat162(__float2bfloat16(vx), __float2bfloat16(vy));
        } else {
            float2 o; o.x = vx; o.y = vy;
            ((float2*)out)[(size_t)row * 48 + c] = o;
        }
    }
}

extern "C" void kernel_launch(void* const* d_in, const int* in_sizes, int n_in,
                              void* d_out, int out_size, void* d_ws, size_t ws_size,
                              hipStream_t stream) {
    const void* x  = d_in[0];
    const int*  ei = (const int*)d_in[1];
    const void* W1 = d_in[2];
    const void* b1 = d_in[3];
    const void* a1 = d_in[4];
    const void* W2 = d_in[5];
    const void* b2 = d_in[6];

    size_t off = 0;
    auto alloc = [&](size_t bytes) { size_t p = off; off = (off + bytes + 255) & ~(size_t)255; return p; };
    char* ws = (char*)d_ws;
    int*            flags  = (int*)           (ws + alloc(1024));
    float*          dinv   = (float*)         (ws + alloc((size_t)NNODES * 4));
    int*            cnt    = (int*)           (ws + alloc((size_t)NNODES * 8)); // cnt+cur contiguous
    int*            cur    = cnt + NNODES;
    int*            rowptr = (int*)           (ws + alloc(((size_t)NNODES + 1) * 4));
    int*            bsum   = (int*)           (ws + alloc((size_t)NB * 4));
    unsigned short* col    = (unsigned short*)(ws + alloc((size_t)NEDGES * 2));
    __hip_bfloat16* g      = (__hip_bfloat16*)(ws + alloc((size_t)NNODES * DIM * 2));
    __hip_bfloat16* g2     = (__hip_bfloat16*)(ws + alloc((size_t)NNODES * DIM * 2));
    if (ws_size < off) return;   // ~21.8 MiB

    k_sniff<<<1, 64, 0, stream>>>((const unsigned*)x, (const unsigned*)ei, flags);

    // ---- CSR build (counting sort by dst) ----
    (void)hipMemsetAsync(cnt, 0, (size_t)NNODES * 8, stream);
    k_count<<<(NEDGES / 2 + 255) / 256, 256, 0, stream>>>(ei, cnt, flags);
    k_scan1<<<NB, SCAN_B, 0, stream>>>(cnt, rowptr, bsum, dinv);
    k_scan2<<<1, SCAN_B, 0, stream>>>(bsum);
    k_scan3<<<NB, SCAN_B, 0, stream>>>(rowptr, bsum);
    k_fill <<<(NEDGES / 2 + 255) / 256, 256, 0, stream>>>(ei, rowptr, cur, col, flags);

    const int gemm_grid = (NNODES + TM - 1) / TM;       // 782
    const int aggr_grid = (NNODES + 3) / 4;             // 12500 (4 rows/block)

    // ---- layer 1 ----
    k_gemm_mfma<<<gemm_grid, 256, 0, stream>>>(x, 0, W1, dinv, g, flags);
    k_aggr<<<aggr_grid, 256, 0, stream>>>(g, rowptr, col, dinv, b1, a1, g2, flags, 1);

    // ---- layer 2 ----
    k_gemm_mfma<<<gemm_grid, 256, 0, stream>>>(g2, 1, W2, dinv, g, flags);
    k_aggr<<<aggr_grid, 256, 0, stream>>>(g, rowptr, col, dinv, b2, a1, d_out, flags, 0);
}

// Round 9
// 257.011 us; speedup vs baseline: 1.2226x; 1.2226x over previous
//
#include <hip/hip_runtime.h>
#include <hip/hip_bf16.h>

// N=50000 nodes, E=800000 edges, D=96 (in = hidden = out)
#define NNODES 50000
#define NEDGES 800000
#define DIM    96
#define NBUCK  196      // ceil(N/256): bucket = dst >> 8
#define PCHUNK 3125     // edges per partition block (256 * 3125 = 800000)
#define TM     64       // rows per GEMM block
#define XPAD   104      // LDS row stride (bf16), 16B-aligned

typedef __attribute__((ext_vector_type(8))) short   short8;   // 8 bf16 = 4 VGPRs
typedef __attribute__((ext_vector_type(4))) float   float4v;  // MFMA acc

// flags[0] = 1 if float tensors are bf16, 0 if f32
// flags[1] = 1 if edge_index is int64, 0 if int32
__device__ __forceinline__ float loadF(const void* p, long i, int isbf) {
    return isbf ? __bfloat162float(((const __hip_bfloat16*)p)[i])
                : ((const float*)p)[i];
}
__device__ __forceinline__ int clampN(int v) {
    return v < 0 ? 0 : (v >= NNODES ? NNODES - 1 : v);
}
__device__ __forceinline__ int edgeDst(const int* w, int e, int is64) {
    return clampN(is64 ? w[2 * (NEDGES + e)] : w[NEDGES + e]);
}
__device__ __forceinline__ int edgeSrc(const int* w, int e, int is64) {
    return clampN(is64 ? w[2 * e] : w[e]);
}

// single wave: sniff x's float dtype and edge_index's int width
__global__ void k_sniff(const unsigned* __restrict__ xw,
                        const unsigned* __restrict__ ew,
                        int* __restrict__ flags) {
    int lane = threadIdx.x;
    int bad = 0, nz = 0;
    for (int r = 0; r < 4; ++r) {
        unsigned w  = xw[lane + 64 * r];
        unsigned lo = w & 0xffffu;
        unsigned ex = (lo >> 7) & 0xffu;
        if (!(lo == 0u || (ex >= 90u && ex <= 145u))) bad++;
        unsigned o = ew[2 * (lane + 64 * r) + 1];
        if (o != 0u) nz++;
    }
    for (int off = 32; off; off >>= 1) {
        bad += __shfl_down(bad, off);
        nz  += __shfl_down(nz,  off);
    }
    if (lane == 0) {
        flags[0] = (bad <= 32) ? 1 : 0;
        flags[1] = (nz  <  4) ? 1 : 0;
    }
}

// bucket counts: per-block LDS histogram, then 196 global adds per block
__global__ __launch_bounds__(256) void k_bcount(const int* __restrict__ w,
                                                int* __restrict__ bcnt,
                                                const int* __restrict__ flags) {
    __shared__ int h[NBUCK];
    const int is64 = flags[1];
    for (int i = threadIdx.x; i < NBUCK; i += 256) h[i] = 0;
    __syncthreads();
    const int nth = gridDim.x * blockDim.x;
    for (int e = blockIdx.x * blockDim.x + threadIdx.x; e < NEDGES; e += nth)
        atomicAdd(&h[edgeDst(w, e, is64) >> 8], 1);
    __syncthreads();
    for (int i = threadIdx.x; i < NBUCK; i += 256)
        if (h[i]) atomicAdd(&bcnt[i], h[i]);
}

// exclusive scan of 196 bucket counts -> bbase, bcur; seal rowptr[N]
__global__ __launch_bounds__(256) void k_bscan(const int* __restrict__ bcnt,
                                               int* __restrict__ bbase,
                                               int* __restrict__ bcur,
                                               int* __restrict__ rowptr) {
    __shared__ int s[256];
    const int tid = threadIdx.x;
    int v = (tid < NBUCK) ? bcnt[tid] : 0;
    s[tid] = v;
    __syncthreads();
    for (int off = 1; off < 256; off <<= 1) {
        int t = (tid >= off) ? s[tid - off] : 0;
        __syncthreads();
        s[tid] += t;
        __syncthreads();
    }
    int excl = s[tid] - v;
    if (tid < NBUCK) { bbase[tid] = excl; bcur[tid] = excl; }
    if (tid == 0) { bbase[NBUCK] = NEDGES; rowptr[NNODES] = NEDGES; }
}

// partition edges into bucket regions as packed (dst<<16)|src u32 records.
// Per-(block,bucket) ranges are contiguous (~64B bursts) -> writes merge in L2.
__global__ __launch_bounds__(256) void k_part(const int* __restrict__ w,
                                              int* __restrict__ bcur,
                                              unsigned* __restrict__ ebuf,
                                              const int* __restrict__ flags) {
    __shared__ int h[NBUCK];
    __shared__ int base[NBUCK];
    const int is64 = flags[1];
    const int e0 = blockIdx.x * PCHUNK;
    const int e1 = (e0 + PCHUNK < NEDGES) ? e0 + PCHUNK : NEDGES;

    for (int i = threadIdx.x; i < NBUCK; i += 256) h[i] = 0;
    __syncthreads();
    for (int e = e0 + threadIdx.x; e < e1; e += 256)
        atomicAdd(&h[edgeDst(w, e, is64) >> 8], 1);
    __syncthreads();
    for (int i = threadIdx.x; i < NBUCK; i += 256) {
        int c = h[i];
        base[i] = c ? atomicAdd(&bcur[i], c) : 0;
        h[i] = 0;                        // reuse as local cursor
    }
    __syncthreads();
    for (int e = e0 + threadIdx.x; e < e1; e += 256) {
        int s = edgeSrc(w, e, is64);
        int d = edgeDst(w, e, is64);
        int b = d >> 8;
        int pos = base[b] + atomicAdd(&h[b], 1);
        ebuf[pos] = ((unsigned)d << 16) | (unsigned)s;
    }
}

// per-bucket local CSR: histogram 256 local dsts, scan -> rowptr/dinv,
// LDS-cursor scatter of col (uint16). All writes block/XCD-local.
__global__ __launch_bounds__(256) void k_csr(const unsigned* __restrict__ ebuf,
                                             const int* __restrict__ bbase,
                                             int* __restrict__ rowptr,
                                             unsigned short* __restrict__ col,
                                             float* __restrict__ dinv) {
    __shared__ int h[256];
    __shared__ int sc[256];
    __shared__ int cur[256];
    const int b   = blockIdx.x;
    const int tid = threadIdx.x;
    const int e0 = bbase[b], e1 = bbase[b + 1];

    h[tid] = 0;
    __syncthreads();
    for (int e = e0 + tid; e < e1; e += 256)
        atomicAdd(&h[(ebuf[e] >> 16) & 255], 1);
    __syncthreads();
    int v = h[tid];
    sc[tid] = v;
    __syncthreads();
    for (int off = 1; off < 256; off <<= 1) {
        int t = (tid >= off) ? sc[tid - off] : 0;
        __syncthreads();
        sc[tid] += t;
        __syncthreads();
    }
    int start = e0 + sc[tid] - v;       // exclusive
    cur[tid] = start;
    int node = b * 256 + tid;
    if (node < NNODES) {
        rowptr[node] = start;
        dinv[node] = rsqrtf((float)v + 1.0f);   // +1 self loop
    }
    __syncthreads();
    for (int e = e0 + tid; e < e1; e += 256) {
        unsigned r = ebuf[e];
        int dl = (r >> 16) & 255;
        int pos = atomicAdd(&cur[dl], 1);
        col[pos] = (unsigned short)(r & 0xffffu);
    }
}

// MFMA GEMM: g[row,:] = bf16( dinv[row] * (X[row,:] @ W) )
// block = 256 (4 waves), 64 rows/block; X strip + W^T staged in LDS as bf16.
__global__ __launch_bounds__(256) void k_gemm_mfma(
        const void* __restrict__ X, int x_force_bf16,
        const void* __restrict__ W,
        const float* __restrict__ dinv,
        __hip_bfloat16* __restrict__ g,
        const int* __restrict__ flags) {
    __shared__ __hip_bfloat16 Xs[TM * XPAD];
    __shared__ __hip_bfloat16 Wt[DIM * XPAD];

    const int t    = threadIdx.x;
    const int fbf  = flags[0];
    const int xbf  = x_force_bf16 ? 1 : fbf;
    const int row0 = blockIdx.x * TM;

    for (int idx = t; idx < DIM * DIM; idx += 256) {
        int k = idx / DIM, n = idx - k * DIM;
        Wt[n * XPAD + k] = __float2bfloat16(loadF(W, idx, fbf));
    }
    for (int idx = t; idx < TM * DIM; idx += 256) {
        int r = idx / DIM, c = idx - r * DIM;
        int gr = row0 + r;
        float v = (gr < NNODES) ? loadF(X, (long)gr * DIM + c, xbf) : 0.f;
        Xs[r * XPAD + c] = __float2bfloat16(v);
    }
    __syncthreads();

    const int wave = t >> 6;
    const int lane = t & 63;
    const int m    = lane & 15;
    const int quad = lane >> 4;

    const short* xsp = (const short*)Xs;
    short8 a[3];
#pragma unroll
    for (int kt = 0; kt < 3; ++kt)
        a[kt] = *(const short8*)(xsp + (wave * 16 + m) * XPAD + kt * 32 + quad * 8);

    float dv[4];
#pragma unroll
    for (int r2 = 0; r2 < 4; ++r2) {
        int gr = row0 + wave * 16 + quad * 4 + r2;
        dv[r2] = (gr < NNODES) ? dinv[gr] : 0.f;
    }

    const short* wtp = (const short*)Wt;
#pragma unroll
    for (int nt = 0; nt < 6; ++nt) {
        float4v acc = {0.f, 0.f, 0.f, 0.f};
#pragma unroll
        for (int kt = 0; kt < 3; ++kt) {
            short8 b = *(const short8*)(wtp + (nt * 16 + m) * XPAD + kt * 32 + quad * 8);
            acc = __builtin_amdgcn_mfma_f32_16x16x32_bf16(a[kt], b, acc, 0, 0, 0);
        }
#pragma unroll
        for (int r2 = 0; r2 < 4; ++r2) {
            int gr = row0 + wave * 16 + quad * 4 + r2;
            if (gr < NNODES)
                g[(size_t)gr * DIM + nt * 16 + m] = __float2bfloat16(acc[r2] * dv[r2]);
        }
    }
}

// aggregate + epilogue: ONE WAVE per destination row, lanes 0..47 hold
// bfloat162 column pairs. col[] reads are wave-uniform.
__global__ __launch_bounds__(256) void k_aggr(
        const __hip_bfloat16* __restrict__ g,
        const int* __restrict__ rowptr,
        const unsigned short* __restrict__ col,
        const float* __restrict__ dinv,
        const void* __restrict__ b,
        const void* __restrict__ a1,
        void* __restrict__ out,
        const int* __restrict__ flags, int prelu) {
    const int wave = threadIdx.x >> 6;
    const int lane = threadIdx.x & 63;
    const int row  = blockIdx.x * 4 + wave;
    if (row >= NNODES) return;                       // wave-uniform
    const int fbf = flags[0];
    const __hip_bfloat162* gv = (const __hip_bfloat162*)g;
    const int c = lane;                              // 0..47 active

    float2 acc = {0.f, 0.f};
    if (c < 48) acc = __bfloat1622float2(gv[(size_t)row * 48 + c]);  // self loop

    const int p0 = rowptr[row], p1 = rowptr[row + 1];
    int i = p0;
    for (; i + 8 <= p1; i += 8) {
        int s0 = col[i+0], s1 = col[i+1], s2 = col[i+2], s3 = col[i+3];
        int s4 = col[i+4], s5 = col[i+5], s6 = col[i+6], s7 = col[i+7];
        if (c < 48) {
            float2 v0 = __bfloat1622float2(gv[(size_t)s0 * 48 + c]);
            float2 v1 = __bfloat1622float2(gv[(size_t)s1 * 48 + c]);
            float2 v2 = __bfloat1622float2(gv[(size_t)s2 * 48 + c]);
            float2 v3 = __bfloat1622float2(gv[(size_t)s3 * 48 + c]);
            float2 v4 = __bfloat1622float2(gv[(size_t)s4 * 48 + c]);
            float2 v5 = __bfloat1622float2(gv[(size_t)s5 * 48 + c]);
            float2 v6 = __bfloat1622float2(gv[(size_t)s6 * 48 + c]);
            float2 v7 = __bfloat1622float2(gv[(size_t)s7 * 48 + c]);
            acc.x += ((v0.x + v1.x) + (v2.x + v3.x)) + ((v4.x + v5.x) + (v6.x + v7.x));
            acc.y += ((v0.y + v1.y) + (v2.y + v3.y)) + ((v4.y + v5.y) + (v6.y + v7.y));
        }
    }
    for (; i < p1; ++i) {
        int s = col[i];
        if (c < 48) {
            float2 v = __bfloat1622float2(gv[(size_t)s * 48 + c]);
            acc.x += v.x; acc.y += v.y;
        }
    }

    if (c < 48) {
        float dv = dinv[row];
        float vx = dv * acc.x + loadF(b, 2 * c,     fbf);
        float vy = dv * acc.y + loadF(b, 2 * c + 1, fbf);
        if (prelu) {
            float alpha = loadF(a1, 0, fbf);
            vx = vx > 0.f ? vx : alpha * vx;
            vy = vy > 0.f ? vy : alpha * vy;
            ((__hip_bfloat162*)out)[(size_t)row * 48 + c] =
                __halves2bfloat162(__float2bfloat16(vx), __float2bfloat16(vy));
        } else if (fbf) {
            ((__hip_bfloat162*)out)[(size_t)row * 48 + c] =
                __halves2bfloat162(__float2bfloat16(vx), __float2bfloat16(vy));
        } else {
            float2 o; o.x = vx; o.y = vy;
            ((float2*)out)[(size_t)row * 48 + c] = o;
        }
    }
}

extern "C" void kernel_launch(void* const* d_in, const int* in_sizes, int n_in,
                              void* d_out, int out_size, void* d_ws, size_t ws_size,
                              hipStream_t stream) {
    const void* x  = d_in[0];
    const int*  ei = (const int*)d_in[1];
    const void* W1 = d_in[2];
    const void* b1 = d_in[3];
    const void* a1 = d_in[4];
    const void* W2 = d_in[5];
    const void* b2 = d_in[6];

    size_t off = 0;
    auto alloc = [&](size_t bytes) { size_t p = off; off = (off + bytes + 255) & ~(size_t)255; return p; };
    char* ws = (char*)d_ws;
    int*            flags  = (int*)           (ws + alloc(1024));
    float*          dinv   = (float*)         (ws + alloc((size_t)NNODES * 4));
    int*            bcnt   = (int*)           (ws + alloc((size_t)NBUCK * 4));
    int*            bbase  = (int*)           (ws + alloc((size_t)(NBUCK + 1) * 4));
    int*            bcur   = (int*)           (ws + alloc((size_t)NBUCK * 4));
    int*            rowptr = (int*)           (ws + alloc(((size_t)NNODES + 1) * 4));
    unsigned*       ebuf   = (unsigned*)      (ws + alloc((size_t)NEDGES * 4));
    unsigned short* col    = (unsigned short*)(ws + alloc((size_t)NEDGES * 2));
    __hip_bfloat16* g      = (__hip_bfloat16*)(ws + alloc((size_t)NNODES * DIM * 2));
    __hip_bfloat16* g2     = (__hip_bfloat16*)(ws + alloc((size_t)NNODES * DIM * 2));
    if (ws_size < off) return;   // ~23.5 MiB

    k_sniff<<<1, 64, 0, stream>>>((const unsigned*)x, (const unsigned*)ei, flags);

    // ---- CSR build: XCD-local 2-pass counting sort by dst ----
    (void)hipMemsetAsync(bcnt, 0, (size_t)NBUCK * 4, stream);
    k_bcount<<<256, 256, 0, stream>>>(ei, bcnt, flags);
    k_bscan <<<1, 256, 0, stream>>>(bcnt, bbase, bcur, rowptr);
    k_part  <<<(NEDGES + PCHUNK - 1) / PCHUNK, 256, 0, stream>>>(ei, bcur, ebuf, flags);
    k_csr   <<<NBUCK, 256, 0, stream>>>(ebuf, bbase, rowptr, col, dinv);

    const int gemm_grid = (NNODES + TM - 1) / TM;       // 782
    const int aggr_grid = (NNODES + 3) / 4;             // 12500 (4 rows/block)

    // ---- layer 1 ----
    k_gemm_mfma<<<gemm_grid, 256, 0, stream>>>(x, 0, W1, dinv, g, flags);
    k_aggr<<<aggr_grid, 256, 0, stream>>>(g, rowptr, col, dinv, b1, a1, g2, flags, 1);

    // ---- layer 2 ----
    k_gemm_mfma<<<gemm_grid, 256, 0, stream>>>(g2, 1, W2, dinv, g, flags);
    k_aggr<<<aggr_grid, 256, 0, stream>>>(g, rowptr, col, dinv, b2, a1, d_out, flags, 0);
}